// Round 8
// baseline (294.923 us; speedup 1.0000x reference)
//
#include <hip/hip_runtime.h>
#include <math.h>

#define B_ 4
#define T_ 16
#define H_ 64
#define W_ 64
#define CIN 32
#define CO 64
#define NG 256   // 4*CO gate channels
#define PXS 40   // padded per-pixel stride in shorts (80 B): 16B-aligned, spreads LDS banks

typedef __attribute__((ext_vector_type(8))) short bf16x8;
typedef __attribute__((ext_vector_type(4))) float f32x4;

__device__ __forceinline__ float hsig(float z) {
    return fminf(1.f, fmaxf(0.f, 0.2f * z + 0.5f));
}

// fast tanh: v_exp_f32 + v_rcp_f32. Saturation exact at +/-inf.
__device__ __forceinline__ float ftanh(float x) {
    float e = __builtin_amdgcn_exp2f(x * 2.8853900817779268f);  // 2*log2(e)
    return 1.f - 2.f * __builtin_amdgcn_rcpf(e + 1.f);
}

__device__ __forceinline__ unsigned short f2bf(float f) {
    union { float f; unsigned u; } v; v.f = f;
    unsigned r = v.u + 0x7FFFu + ((v.u >> 16) & 1u);   // RTNE
    return (unsigned short)(r >> 16);
}

// Transpose+convert weights once per launch:
//   wkT[kpos][n=256][k=32]        from wk (3,3,32,256)
//   wrT[kpos][q=2][n=256][k=32]   from wr (3,3,64,256), q = cin chunk of 32
__global__ void transform_weights(const float* __restrict__ wk,
                                  const float* __restrict__ wr,
                                  unsigned short* __restrict__ wkT,
                                  unsigned short* __restrict__ wrT)
{
    int i = blockIdx.x * 256 + threadIdx.x;
    if (i < 9 * 256 * 32) {
        int k = i & 31, n = (i >> 5) & 255, kpos = i >> 13;
        wkT[i] = f2bf(wk[(kpos * 32 + k) * 256 + n]);
    }
    if (i < 9 * 2 * 256 * 32) {
        int k = i & 31, n = (i >> 5) & 255, q = (i >> 13) & 1, kpos = i >> 14;
        wrT[i] = f2bf(wr[(kpos * 64 + q * 32 + k) * 256 + n]);
    }
}

// One timestep. Block = 64 px (4 rows x 16 cols), 768 threads = 12 waves =
// 3 wave-groups (wg = wv>>2) x 4 n-slices (sl = wv&3) -> 3 waves/SIMD.
// Chunk split (27 chunks = 9 x-conv + 18 h-conv(kpos,q)):
//   wg0: chunks 0-8  (x-conv, src sx, wkT)
//   wg1: chunks 9-17 (h-conv (c-9)=0..8, src sh[q], wrT)
//   wg2: chunks 18-26
// Per-block weight traffic unchanged (each chunk read once). Single-barrier
// 3-way merge via 128 KB LDS exchange; epilogue rows: wg0:{0,1} wg1:{2} wg2:{3}.
// RULE #20: acc[][] only ever indexed with literals (3 uniform branch arms).
template<bool FIRST>
__global__ __launch_bounds__(768, 3)
void convlstm_step(const float* __restrict__ x,
                   const unsigned short* __restrict__ wkT,
                   const unsigned short* __restrict__ wrT,
                   const float* __restrict__ bias,
                   const float* __restrict__ gamma,
                   const float* __restrict__ beta,
                   const float* __restrict__ mean,
                   const float* __restrict__ var,
                   const unsigned short* __restrict__ hin,   // bf16 NHWC
                   unsigned short* __restrict__ hout,        // bf16 NHWC
                   float* __restrict__ cbuf,
                   float* __restrict__ out,
                   int t)
{
    __shared__ __align__(16) unsigned short sx[6 * 18 * PXS];        //  8.6 KB
    __shared__ __align__(16) unsigned short shm[2][6 * 18 * PXS];    // 17.3 KB
    // 3-way partial exchange: [sl4][g4][slot8][ln16][16f] fp32 = 128 KB
    // slots: row0:{wg1->0,wg2->1} row1:{wg1->2,wg2->3} row2:{wg0->4,wg2->5} row3:{wg0->6,wg1->7}
    __shared__ __align__(16) float axx[4 * 4 * 8 * 256];

    const int tid = threadIdx.x;
    const int wv = tid >> 6, lane = tid & 63;
    const int ln = lane & 15, kg = lane >> 4;
    const int wg = wv >> 2;                // 0,1,2
    const int sl = wv & 3;                 // n-slice: ch = sl*16 + ln

    const int bi = blockIdx.x;
    const int b = bi >> 6, tile = bi & 63;
    const int oy = (tile >> 2) * 4;        // 16 row-tiles
    const int ox = (tile & 3) * 16;        // 4 col-tiles

    unsigned short* sh0 = shm[0];
    unsigned short* sh1 = shm[1];

    // ---- parallel staging: wg2 stages sx (256 thr), waves 0-7 stage sh ----
    if (wg == 2) {
        // x halo (fp32 -> bf16): 108 positions x 4 chunks of 8 cin = 432 elems
#pragma unroll
        for (int i = 0; i < 2; ++i) {
            int e = (tid - 512) + i * 256;
            if (e < 432) {
                int c8 = e & 3, p = e >> 2;
                int row = p / 18, col = p - row * 18;
                int gy = oy - 1 + row, gx = ox - 1 + col;
                float4 v0 = make_float4(0.f, 0.f, 0.f, 0.f), v1 = v0;
                if ((unsigned)gy < (unsigned)H_ && (unsigned)gx < (unsigned)W_) {
                    const float* p32 = &x[((((size_t)b * T_ + t) * H_ + gy) * W_ + gx) * CIN + c8 * 8];
                    v0 = *(const float4*)p32; v1 = *(const float4*)(p32 + 4);
                }
                unsigned short* d = &sx[(row * 18 + col) * PXS + c8 * 8];
                d[0] = f2bf(v0.x); d[1] = f2bf(v0.y); d[2] = f2bf(v0.z); d[3] = f2bf(v0.w);
                d[4] = f2bf(v1.x); d[5] = f2bf(v1.y); d[6] = f2bf(v1.z); d[7] = f2bf(v1.w);
            }
        }
    } else if (!FIRST) {
        // h halo (bf16 copy): 108 positions x 8 octs of 8 ch = 864 elems, 512 thr
#pragma unroll
        for (int i = 0; i < 2; ++i) {
            int e = tid + i * 512;
            if (e < 864) {
                int o = e & 7, p = e >> 3;
                int row = p / 18, col = p - row * 18;
                int gy = oy - 1 + row, gx = ox - 1 + col;
                uint4 v = make_uint4(0u, 0u, 0u, 0u);
                if ((unsigned)gy < (unsigned)H_ && (unsigned)gx < (unsigned)W_)
                    v = *(const uint4*)&hin[(((size_t)b * H_ + gy) * W_ + gx) * CO + o * 8];
                int q = o >> 2, s4 = o & 3;
                *(uint4*)&shm[q][(row * 18 + col) * PXS + s4 * 8] = v;
            }
        }
    }

    const int ch = sl * 16 + ln;
    const unsigned short* wkp = wkT + (size_t)ch * 32 + kg * 8;
    const unsigned short* wrp = wrT + (size_t)ch * 32 + kg * 8;

    // ---- hoisted epilogue inputs (each wg: its own epilogue rows) ----
    const float bi0 = bias[ch], bi1 = bias[64 + ch], bi2 = bias[128 + ch], bi3 = bias[192 + ch];
    const float inv = gamma[ch] * rsqrtf(var[ch] + 1e-3f);
    const float shift = beta[ch] - mean[ch] * inv;
    float cpv[2][4];
#pragma unroll
    for (int rr = 0; rr < 2; ++rr)
#pragma unroll
        for (int reg = 0; reg < 4; ++reg) cpv[rr][reg] = 0.f;
    if (!FIRST) {
        if (wg == 0) {
#pragma unroll
            for (int reg = 0; reg < 4; ++reg) {
                size_t pix0 = ((size_t)b * H_ + oy + 0) * W_ + (ox + kg * 4 + reg);
                size_t pix1 = ((size_t)b * H_ + oy + 1) * W_ + (ox + kg * 4 + reg);
                cpv[0][reg] = cbuf[pix0 * CO + ch];
                cpv[1][reg] = cbuf[pix1 * CO + ch];
            }
        } else {
            const int r = (wg == 1) ? 2 : 3;
#pragma unroll
            for (int reg = 0; reg < 4; ++reg) {
                size_t pix = ((size_t)b * H_ + oy + r) * W_ + (ox + kg * 4 + reg);
                cpv[0][reg] = cbuf[pix * CO + ch];
            }
        }
    }

    __syncthreads();

    f32x4 acc[4][4];   // [gate][row] -- LITERAL indices only
#pragma unroll
    for (int g = 0; g < 4; ++g)
#pragma unroll
        for (int r = 0; r < 4; ++r) acc[g][r] = (f32x4){0.f, 0.f, 0.f, 0.f};

// ---- chunk maps (literal c constant-folds) ----
#define WPTR(c) ((c) < 9 ? (wkp + (size_t)(c) * 8192) : (wrp + (size_t)((c) - 9) * 8192))
#define SRCB(c) ((c) < 9 ? sx : ((((c) - 9) & 1) ? sh1 : sh0))
#define KP(c)   ((c) < 9 ? (c) : (((c) - 9) >> 1))

#define CHUNK(c) {                                                               \
    const unsigned short* wp_ = WPTR(c);                                         \
    bf16x8 w0 = *(const bf16x8*)(wp_);                                           \
    bf16x8 w1 = *(const bf16x8*)(wp_ + 2048);                                    \
    bf16x8 w2 = *(const bf16x8*)(wp_ + 4096);                                    \
    bf16x8 w3 = *(const bf16x8*)(wp_ + 6144);                                    \
    const int ky_ = KP(c) / 3, kx_ = KP(c) - (KP(c) / 3) * 3;                    \
    const unsigned short* sb_ = SRCB(c);                                         \
    bf16x8 a0 = *(const bf16x8*)&sb_[((0 + ky_) * 18 + ln + kx_) * PXS + kg * 8];\
    bf16x8 a1 = *(const bf16x8*)&sb_[((1 + ky_) * 18 + ln + kx_) * PXS + kg * 8];\
    bf16x8 a2 = *(const bf16x8*)&sb_[((2 + ky_) * 18 + ln + kx_) * PXS + kg * 8];\
    bf16x8 a3 = *(const bf16x8*)&sb_[((3 + ky_) * 18 + ln + kx_) * PXS + kg * 8];\
    __builtin_amdgcn_s_setprio(1);                                               \
    acc[0][0] = __builtin_amdgcn_mfma_f32_16x16x32_bf16(a0, w0, acc[0][0], 0, 0, 0); \
    acc[0][1] = __builtin_amdgcn_mfma_f32_16x16x32_bf16(a1, w0, acc[0][1], 0, 0, 0); \
    acc[0][2] = __builtin_amdgcn_mfma_f32_16x16x32_bf16(a2, w0, acc[0][2], 0, 0, 0); \
    acc[0][3] = __builtin_amdgcn_mfma_f32_16x16x32_bf16(a3, w0, acc[0][3], 0, 0, 0); \
    acc[1][0] = __builtin_amdgcn_mfma_f32_16x16x32_bf16(a0, w1, acc[1][0], 0, 0, 0); \
    acc[1][1] = __builtin_amdgcn_mfma_f32_16x16x32_bf16(a1, w1, acc[1][1], 0, 0, 0); \
    acc[1][2] = __builtin_amdgcn_mfma_f32_16x16x32_bf16(a2, w1, acc[1][2], 0, 0, 0); \
    acc[1][3] = __builtin_amdgcn_mfma_f32_16x16x32_bf16(a3, w1, acc[1][3], 0, 0, 0); \
    acc[2][0] = __builtin_amdgcn_mfma_f32_16x16x32_bf16(a0, w2, acc[2][0], 0, 0, 0); \
    acc[2][1] = __builtin_amdgcn_mfma_f32_16x16x32_bf16(a1, w2, acc[2][1], 0, 0, 0); \
    acc[2][2] = __builtin_amdgcn_mfma_f32_16x16x32_bf16(a2, w2, acc[2][2], 0, 0, 0); \
    acc[2][3] = __builtin_amdgcn_mfma_f32_16x16x32_bf16(a3, w2, acc[2][3], 0, 0, 0); \
    acc[3][0] = __builtin_amdgcn_mfma_f32_16x16x32_bf16(a0, w3, acc[3][0], 0, 0, 0); \
    acc[3][1] = __builtin_amdgcn_mfma_f32_16x16x32_bf16(a1, w3, acc[3][1], 0, 0, 0); \
    acc[3][2] = __builtin_amdgcn_mfma_f32_16x16x32_bf16(a2, w3, acc[3][2], 0, 0, 0); \
    acc[3][3] = __builtin_amdgcn_mfma_f32_16x16x32_bf16(a3, w3, acc[3][3], 0, 0, 0); \
    __builtin_amdgcn_s_setprio(0); }

    if (wg == 0) {
        CHUNK(0) CHUNK(1) CHUNK(2) CHUNK(3) CHUNK(4) CHUNK(5) CHUNK(6) CHUNK(7) CHUNK(8)
    } else if (wg == 1) {
        if (!FIRST) {
            CHUNK(9) CHUNK(10) CHUNK(11) CHUNK(12) CHUNK(13) CHUNK(14) CHUNK(15) CHUNK(16) CHUNK(17)
        }
    } else {
        if (!FIRST) {
            CHUNK(18) CHUNK(19) CHUNK(20) CHUNK(21) CHUNK(22) CHUNK(23) CHUNK(24) CHUNK(25) CHUNK(26)
        }
    }

    // ---- publish partials (literal slots/rows per wg arm) ----
    const int axo = (ln << 4) + (kg << 2);   // lane's 16B cell within a slot
#define AXPUB(s, G, R) *(f32x4*)&axx[(((sl * 4 + (G)) * 8 + (s)) << 8) + axo] = acc[G][R];
#define AXRD(s, G)     (*(const f32x4*)&axx[(((sl * 4 + (G)) * 8 + (s)) << 8) + axo])

    if (wg == 0) {
#pragma unroll
        for (int g = 0; g < 4; ++g) { AXPUB(4, g, 2) AXPUB(6, g, 3) }
    } else if (wg == 1) {
#pragma unroll
        for (int g = 0; g < 4; ++g) { AXPUB(0, g, 0) AXPUB(2, g, 1) AXPUB(7, g, 3) }
    } else {
#pragma unroll
        for (int g = 0; g < 4; ++g) { AXPUB(1, g, 0) AXPUB(3, g, 1) AXPUB(5, g, 2) }
    }
    __syncthreads();

    // ---- merge + epilogue, literal rows per wg ----
#define EPI(R, CPI, S0, S1) {                                                    \
        const int gy = oy + (R);                                                 \
        f32x4 av[4];                                                             \
        _Pragma("unroll")                                                        \
        for (int g = 0; g < 4; ++g)                                              \
            av[g] = acc[g][R] + AXRD(S0, g) + AXRD(S1, g);                       \
        _Pragma("unroll")                                                        \
        for (int reg = 0; reg < 4; ++reg) {                                      \
            const int gx = ox + kg * 4 + reg;                                    \
            size_t pix = ((size_t)b * H_ + gy) * W_ + gx;                        \
            float ig = hsig(av[0][reg] + bi0);                                   \
            float fg = hsig(av[1][reg] + bi1);                                   \
            float cg = ftanh(av[2][reg] + bi2);                                  \
            float og = hsig(av[3][reg] + bi3);                                   \
            float cv = fg * cpv[CPI][reg] + ig * cg;                             \
            float hv = og * ftanh(cv);                                           \
            cbuf[pix * CO + ch] = cv;                                            \
            hout[pix * CO + ch] = f2bf(hv);                                      \
            __builtin_nontemporal_store(hv * inv + shift,                        \
                &out[((((size_t)b * T_ + t) * H_ + gy) * W_ + gx) * CO + ch]);   \
        }                                                                        \
    }

    if (wg == 0)      { EPI(0, 0, 0, 1) EPI(1, 1, 2, 3) }
    else if (wg == 1) { EPI(2, 0, 4, 5) }
    else              { EPI(3, 0, 6, 7) }
#undef EPI
#undef AXPUB
#undef AXRD
#undef CHUNK
#undef WPTR
#undef SRCB
#undef KP
}

extern "C" void kernel_launch(void* const* d_in, const int* in_sizes, int n_in,
                              void* d_out, int out_size, void* d_ws, size_t ws_size,
                              hipStream_t stream)
{
    (void)in_sizes; (void)n_in; (void)out_size; (void)ws_size;
    const float* x     = (const float*)d_in[0];
    const float* wk    = (const float*)d_in[1];
    const float* wr    = (const float*)d_in[2];
    const float* bias  = (const float*)d_in[3];
    const float* gamma = (const float*)d_in[4];
    const float* beta  = (const float*)d_in[5];
    const float* mean  = (const float*)d_in[6];
    const float* var   = (const float*)d_in[7];
    float* out = (float*)d_out;

    const size_t plane = (size_t)B_ * H_ * W_ * CO;           // 1,048,576 elems
    unsigned short* h0 = (unsigned short*)d_ws;               // bf16, 2 MB
    unsigned short* h1 = h0 + plane;                          // bf16, 2 MB
    float* cb = (float*)(h1 + plane);                         // fp32, 4 MB
    unsigned short* wkT = (unsigned short*)(cb + plane);      // 147 KB
    unsigned short* wrT = wkT + 9 * 256 * 32;                 // 295 KB

    transform_weights<<<576, 256, 0, stream>>>(wk, wr, wkT, wrT);

    for (int t = 0; t < T_; ++t) {
        const unsigned short* hin = (t & 1) ? h0 : h1;  // garbage at t==0 (unused)
        unsigned short* houtp     = (t & 1) ? h1 : h0;
        if (t == 0)
            convlstm_step<true><<<256, 768, 0, stream>>>(x, wkT, wrT, bias, gamma, beta, mean, var,
                                                         hin, houtp, cb, out, t);
        else
            convlstm_step<false><<<256, 768, 0, stream>>>(x, wkT, wrT, bias, gamma, beta, mean, var,
                                                          hin, houtp, cb, out, t);
    }
}